// Round 1
// baseline (3565.228 us; speedup 1.0000x reference)
//
#include <hip/hip_runtime.h>
#include <hip/hip_bf16.h>
#include <cstdint>
#include <cstddef>

typedef unsigned short u16;
typedef __attribute__((ext_vector_type(8))) short s8v;     // 8 bf16 (A/B frag)
typedef __attribute__((ext_vector_type(4))) float f4v;     // C/D frag
typedef __attribute__((ext_vector_type(4))) unsigned short u16x4;

#define MFMA(A,B,C) __builtin_amdgcn_mfma_f32_16x16x32_bf16((A),(B),(C),0,0,0)

__device__ __forceinline__ u16 f2b(float f){
  union{float f; uint32_t u;} v; v.f=f;
  return (u16)((v.u + 0x7FFFu + ((v.u>>16)&1u))>>16);   // RNE
}

__device__ __forceinline__ void glds16(const u16* g, u16* l){
  __builtin_amdgcn_global_load_lds((const __attribute__((address_space(1))) uint32_t*)g,
                                   (__attribute__((address_space(3))) uint32_t*)l, 16, 0, 0);
}

// ---------------- elementwise f32 -> bf16 ----------------
__global__ void k_cvt_bf16(const float* __restrict__ src, u16* __restrict__ dst, int n4){
  int i = blockIdx.x*256 + threadIdx.x;
  if(i < n4){
    float4 v = ((const float4*)src)[i];
    u16x4 o; o.x=f2b(v.x); o.y=f2b(v.y); o.z=f2b(v.z); o.w=f2b(v.w);
    ((u16x4*)dst)[i] = o;
  }
}

// ---------------- mask -> additive bias ----------------
__global__ void k_maskbias(const unsigned char* __restrict__ m, float* __restrict__ dst, int n){
  int i = blockIdx.x*256 + threadIdx.x;
  if(i<n) dst[i] = m[i] ? -1e30f : 0.0f;
}

// ---------------- bias concat ----------------
__global__ void k_concat3(float* __restrict__ dst, const float* a, int na,
                          const float* b, int nb, const float* c, int nc){
  int i = blockIdx.x*256 + threadIdx.x;
  int n = na+nb+nc;
  if(i>=n) return;
  dst[i] = (i<na) ? a[i] : (i<na+nb) ? b[i-na] : c[i-na-nb];
}

// ---------------- transpose+cvt: src[K][N] f32 -> dst[N][K] bf16 ----------------
__global__ void k_transpose_cvt(const float* __restrict__ src, u16* __restrict__ dst, int K, int N){
  __shared__ float t[32][33];
  int nb = blockIdx.x*32, kb = blockIdx.y*32;
  int tx = threadIdx.x, ty = threadIdx.y;          // (32,8)
#pragma unroll
  for(int i=0;i<32;i+=8) t[ty+i][tx] = src[(size_t)(kb+ty+i)*N + nb+tx];
  __syncthreads();
#pragma unroll
  for(int i=0;i<32;i+=8) dst[(size_t)(nb+ty+i)*K + kb+tx] = f2b(t[tx][ty+i]);
}

// ---------------- per-head transpose+cvt: src[H][K][64] f32 -> dst[H][64][K] bf16 ----------------
__global__ void k_transpose_cvt_head(const float* __restrict__ src, u16* __restrict__ dst, int K){
  __shared__ float t[32][33];
  const float* s = src + (size_t)blockIdx.z*K*64;
  u16* d = dst + (size_t)blockIdx.z*64*K;
  int kb = blockIdx.x*32, db = blockIdx.y*32;
  int tx=threadIdx.x, ty=threadIdx.y;
#pragma unroll
  for(int i=0;i<32;i+=8) t[ty+i][tx] = s[(size_t)(kb+ty+i)*64 + db+tx];
  __syncthreads();
#pragma unroll
  for(int i=0;i<32;i+=8) d[(size_t)(db+ty+i)*K + kb+tx] = f2b(t[tx][ty+i]);
}

// ---------------- V transpose: src[b*1024+s][lds_] cols col0+h*64+d -> dst[(b*16+h)*64+d][1024] ----------------
__global__ void k_transpose_v(const u16* __restrict__ src, int lds_, int col0, u16* __restrict__ dst){
  __shared__ u16 t[32][33];
  int bh = blockIdx.z; int b = bh>>4, h = bh&15;
  int s0 = blockIdx.x*32, d0 = blockIdx.y*32;
  int tx=threadIdx.x, ty=threadIdx.y;
#pragma unroll
  for(int i=0;i<32;i+=8)
    t[ty+i][tx] = src[(size_t)(b*1024 + s0+ty+i)*lds_ + col0 + h*64 + d0+tx];
  __syncthreads();
#pragma unroll
  for(int i=0;i<32;i+=8)
    dst[((size_t)bh*64 + d0+ty+i)*1024 + s0+tx] = t[tx][ty+i];
}

// ---------------- m97-style GEMM: C[4096][N] = A[4096][K] @ Bt[N][K]^T ----------------
// out = alpha*(A@B + bias[col]) (+ resid[row*N+col]) ; optional relu; out bf16 or f32
template<bool OUTBF, bool RELU, bool RESID>
__global__ __launch_bounds__(256)
void k_gemm_bt(const u16* __restrict__ Ag_, const u16* __restrict__ Bg_,
               const float* __restrict__ bias, const float* __restrict__ resid,
               void* __restrict__ Cout, int N, int K, float alpha)
{
  __shared__ __align__(16) u16 lA[128*32];
  __shared__ __align__(16) u16 lB[128*32];
  const int tid = threadIdx.x;
  const int wave = tid>>6, lane = tid&63;
  const int m_ = lane&15, qd = lane>>4;
  const int wm = wave&1, wn = wave>>1;
  const int m0 = blockIdx.y<<7, n0 = blockIdx.x<<7;

  f4v acc[4][4];
#pragma unroll
  for(int i2=0;i2<4;i2++)
#pragma unroll
    for(int j=0;j<4;j++){ f4v z={0.f,0.f,0.f,0.f}; acc[i2][j]=z; }

  const u16* Ag = Ag_ + (size_t)(m0 + (lane>>2))*K + (lane&3)*8;
  const u16* Bg = Bg_ + (size_t)(n0 + (lane>>2))*K + (lane&3)*8;
  u16* lA0 = lA + wave*512;  u16* lA1 = lA + (wave+4)*512;
  u16* lB0 = lB + wave*512;  u16* lB1 = lB + (wave+4)*512;
  const size_t rsk0 = (size_t)wave*16*K, rsk1 = (size_t)(wave+4)*16*K;

  for(int k0=0; k0<K; k0+=32){
    glds16(Ag + rsk0 + k0, lA0);
    glds16(Ag + rsk1 + k0, lA1);
    glds16(Bg + rsk0 + k0, lB0);
    glds16(Bg + rsk1 + k0, lB1);
    __syncthreads();
    s8v af[4], bf[4];
#pragma unroll
    for(int t=0;t<4;t++) af[t] = *(const s8v*)&lA[((wm<<6) + (t<<4) + m_)*32 + (qd<<3)];
#pragma unroll
    for(int t=0;t<4;t++) bf[t] = *(const s8v*)&lB[((wn<<6) + (t<<4) + m_)*32 + (qd<<3)];
#pragma unroll
    for(int i2=0;i2<4;i2++)
#pragma unroll
      for(int j=0;j<4;j++) acc[i2][j] = MFMA(af[i2], bf[j], acc[i2][j]);
    __syncthreads();
  }

#pragma unroll
  for(int i2=0;i2<4;i2++){
    const int row_b = m0 + (wm<<6) + (i2<<4) + (qd<<2);
#pragma unroll
    for(int j=0;j<4;j++){
      const int col = n0 + (wn<<6) + (j<<4) + m_;
      const float bv = bias[col];
#pragma unroll
      for(int r=0;r<4;r++){
        const int row = row_b + r;
        float v = (acc[i2][j][r] + bv)*alpha;
        if(RESID) v += resid[(size_t)row*N + col];
        if(RELU)  v = fmaxf(v, 0.0f);
        if(OUTBF) ((u16*)Cout)[(size_t)row*N + col] = f2b(v);
        else      ((float*)Cout)[(size_t)row*N + col] = v;
      }
    }
  }
}

// ---------------- flash attention + fused per-head wh linear ----------------
// grid (S/64, B*H); Q rows 64 per block (16/wave); K,V tiled by 32.
// Out[b*1024+q][h*64+j] = ( softmax(Q K^T /8 + maskbias) V ) @ wh[h] + bh[h]
__global__ __launch_bounds__(256)
void k_flash(const u16* __restrict__ Q, int ldq,
             const u16* __restrict__ Kc, int ldk,
             const u16* __restrict__ Vt,
             const u16* __restrict__ wh_t, const float* __restrict__ bh,
             const float* __restrict__ maskb,
             u16* __restrict__ Out)
{
  __shared__ __align__(16) u16 lK[32*72];
  __shared__ __align__(16) u16 lV[64*40];
  __shared__ __align__(16) u16 lP[4*16*40];
  __shared__ __align__(16) u16 lO[4*16*72];
  __shared__ __align__(16) float lMB[1024];

  const int tid = threadIdx.x;
  const int wave = tid>>6, lane = tid&63;
  const int m_ = lane&15, qd = lane>>4;
  const int bh_ = blockIdx.y; const int b = bh_>>4, h = bh_&15;
  const int q0 = blockIdx.x<<6;

  ((float4*)lMB)[tid] = ((const float4*)(maskb + (size_t)b*1024))[tid];

  const u16* qp = Q + (size_t)(b*1024 + q0 + wave*16 + m_)*ldq + h*64 + (qd<<3);
  s8v qa0 = *(const s8v*)qp;
  s8v qa1 = *(const s8v*)(qp + 32);

  f4v o[4];
#pragma unroll
  for(int nt=0;nt<4;nt++){ f4v z={0.f,0.f,0.f,0.f}; o[nt]=z; }
  float mi[4], li[4];
#pragma unroll
  for(int r=0;r<4;r++){ mi[r]=-1e20f; li[r]=0.0f; }

  const u16* Kbase = Kc + (size_t)(b*1024)*ldk + h*64;
  const u16* Vbase = Vt + (size_t)bh_*64*1024;
  u16* lPw = lP + wave*640;

  for(int t0=0; t0<1024; t0+=32){
    { // stage K (32x64, stride 72) and V (64x32, stride 40)
      int r = tid>>3, j = tid&7;
      *(s8v*)&lK[r*72 + (j<<3)] = *(const s8v*)(Kbase + (size_t)(t0+r)*ldk + (j<<3));
      int d = tid>>2, jc = tid&3;
      *(s8v*)&lV[d*40 + (jc<<3)] = *(const s8v*)(Vbase + (size_t)d*1024 + t0 + (jc<<3));
    }
    __syncthreads();

    f4v s0={0.f,0.f,0.f,0.f}, s1={0.f,0.f,0.f,0.f};
    {
      s8v kb00 = *(const s8v*)&lK[(m_)*72      + (qd<<3)];
      s8v kb01 = *(const s8v*)&lK[(m_)*72      + ((4+qd)<<3)];
      s8v kb10 = *(const s8v*)&lK[(16+m_)*72   + (qd<<3)];
      s8v kb11 = *(const s8v*)&lK[(16+m_)*72   + ((4+qd)<<3)];
      s0 = MFMA(qa0, kb00, s0); s0 = MFMA(qa1, kb01, s0);
      s1 = MFMA(qa0, kb10, s1); s1 = MFMA(qa1, kb11, s1);
    }
    const float bv0 = lMB[t0 + m_], bv1 = lMB[t0 + 16 + m_];
#pragma unroll
    for(int r=0;r<4;r++){ s0[r] = s0[r]*0.125f + bv0; s1[r] = s1[r]*0.125f + bv1; }

#pragma unroll
    for(int r=0;r<4;r++){
      float rm = fmaxf(s0[r], s1[r]);
      rm = fmaxf(rm, __shfl_xor(rm, 1)); rm = fmaxf(rm, __shfl_xor(rm, 2));
      rm = fmaxf(rm, __shfl_xor(rm, 4)); rm = fmaxf(rm, __shfl_xor(rm, 8));
      const float mn = fmaxf(mi[r], rm);
      const float al = __expf(mi[r] - mn);
      mi[r] = mn;
      const float p0 = __expf(s0[r]-mn), p1 = __expf(s1[r]-mn);
      float rs = p0 + p1;
      rs += __shfl_xor(rs,1); rs += __shfl_xor(rs,2);
      rs += __shfl_xor(rs,4); rs += __shfl_xor(rs,8);
      li[r] = li[r]*al + rs;
      o[0][r]*=al; o[1][r]*=al; o[2][r]*=al; o[3][r]*=al;
      lPw[((qd<<2)+r)*40 + m_]      = f2b(p0);
      lPw[((qd<<2)+r)*40 + 16 + m_] = f2b(p1);
    }
    // wave-local LDS round-trip: C-layout -> A-layout
    s8v pa = *(const s8v*)&lPw[m_*40 + (qd<<3)];
#pragma unroll
    for(int nt=0; nt<4; nt++){
      s8v vb = *(const s8v*)&lV[((nt<<4)+m_)*40 + (qd<<3)];
      o[nt] = MFMA(pa, vb, o[nt]);
    }
    __syncthreads();
  }

#pragma unroll
  for(int nt=0;nt<4;nt++)
#pragma unroll
    for(int r=0;r<4;r++) o[nt][r] /= li[r];

  // fused wh: write O (16x64) to LDS as A-operand, MFMA with wh_t[h] ([j][dk])
  u16* lOw = lO + wave*1152;
#pragma unroll
  for(int nt=0;nt<4;nt++)
#pragma unroll
    for(int r=0;r<4;r++)
      lOw[((qd<<2)+r)*72 + (nt<<4) + m_] = f2b(o[nt][r]);

  s8v oa0 = *(const s8v*)&lOw[m_*72 + (qd<<3)];
  s8v oa1 = *(const s8v*)&lOw[m_*72 + 32 + (qd<<3)];
  const u16* whp = wh_t + (size_t)h*64*64;
  f4v c2[4];
#pragma unroll
  for(int nt=0;nt<4;nt++){
    s8v wb0 = *(const s8v*)(whp + (size_t)((nt<<4)+m_)*64 + (qd<<3));
    s8v wb1 = *(const s8v*)(whp + (size_t)((nt<<4)+m_)*64 + 32 + (qd<<3));
    f4v z={0.f,0.f,0.f,0.f};
    z = MFMA(oa0, wb0, z);
    z = MFMA(oa1, wb1, z);
    c2[nt]=z;
  }
#pragma unroll
  for(int nt=0;nt<4;nt++){
    const int col = h*64 + (nt<<4) + m_;
    const float bb = bh[col];
#pragma unroll
    for(int r=0;r<4;r++){
      const int row = b*1024 + q0 + wave*16 + (qd<<2) + r;
      Out[(size_t)row*1024 + col] = f2b(c2[nt][r] + bb);
    }
  }
}

// ---------------- layernorm over 1024, dual-output (f32 + bf16) ----------------
__global__ __launch_bounds__(256)
void k_layernorm(const float* __restrict__ z, const float* __restrict__ g, const float* __restrict__ be,
                 float* __restrict__ outf, u16* __restrict__ outb)
{
  const int row = blockIdx.x, tid = threadIdx.x;
  const float4 x4 = ((const float4*)(z + (size_t)row*1024))[tid];
  float s  = x4.x + x4.y + x4.z + x4.w;
  float ss = x4.x*x4.x + x4.y*x4.y + x4.z*x4.z + x4.w*x4.w;
#pragma unroll
  for(int off=32; off; off>>=1){ s += __shfl_down(s,off); ss += __shfl_down(ss,off); }
  __shared__ float red[8];
  const int wave = tid>>6, lane = tid&63;
  if(lane==0){ red[wave]=s; red[4+wave]=ss; }
  __syncthreads();
  if(tid==0){
    float S=red[0]+red[1]+red[2]+red[3], SS=red[4]+red[5]+red[6]+red[7];
    float mu = S*(1.0f/1024.0f);
    float var = SS*(1.0f/1024.0f) - mu*mu;
    red[0]=mu; red[1]=rsqrtf(var + 1e-5f);
  }
  __syncthreads();
  const float mu=red[0], rs=red[1];
  const float4 g4 = ((const float4*)g)[tid];
  const float4 b4 = ((const float4*)be)[tid];
  float4 ov;
  ov.x = (x4.x-mu)*rs*g4.x + b4.x;
  ov.y = (x4.y-mu)*rs*g4.y + b4.y;
  ov.z = (x4.z-mu)*rs*g4.z + b4.z;
  ov.w = (x4.w-mu)*rs*g4.w + b4.w;
  ((float4*)(outf + (size_t)row*1024))[tid] = ov;
  u16x4 ob; ob.x=f2b(ov.x); ob.y=f2b(ov.y); ob.z=f2b(ov.z); ob.w=f2b(ov.w);
  ((u16x4*)(outb + (size_t)row*1024))[tid] = ob;
}

// =======================================================================
extern "C" void kernel_launch(void* const* d_in, const int* in_sizes, int n_in,
                              void* d_out, int out_size, void* d_ws, size_t ws_size,
                              hipStream_t stream)
{
  const float* x_in = (const float*)d_in[0];
  const float* bert = (const float*)d_in[1];
  const unsigned char* maskc = (const unsigned char*)d_in[2];
  const float* s_wq=(const float*)d_in[3];  const float* s_bq=(const float*)d_in[4];
  const float* s_wk=(const float*)d_in[5];  const float* s_bk=(const float*)d_in[6];
  const float* s_wv=(const float*)d_in[7];  const float* s_bv=(const float*)d_in[8];
  const float* s_wh=(const float*)d_in[9];  const float* s_bh=(const float*)d_in[10];
  const float* s_wo=(const float*)d_in[11]; const float* s_bo=(const float*)d_in[12];
  const float* b_wq=(const float*)d_in[13]; const float* b_bq=(const float*)d_in[14];
  const float* b_wk=(const float*)d_in[15]; const float* b_bk=(const float*)d_in[16];
  const float* b_wv=(const float*)d_in[17]; const float* b_bv=(const float*)d_in[18];
  const float* b_wh=(const float*)d_in[19]; const float* b_bh=(const float*)d_in[20];
  const float* b_wo=(const float*)d_in[21]; const float* b_bo=(const float*)d_in[22];
  const float* w1 =(const float*)d_in[23];  const float* b1 =(const float*)d_in[24];
  const float* w2 =(const float*)d_in[25];  const float* b2 =(const float*)d_in[26];
  const float* ln1g=(const float*)d_in[27]; const float* ln1b=(const float*)d_in[28];
  const float* ln2g=(const float*)d_in[29]; const float* ln2b=(const float*)d_in[30];

  char* p = (char*)d_ws;
  size_t off = 0;
  auto A = [&](size_t nbytes)->void*{ void* q = p + off; off += nbytes; off = (off+255)&~(size_t)255; return q; };

  u16* wqkv_t=(u16*)A(3072ull*1024*2);
  u16* wqb_t =(u16*)A(1024ull*1024*2);
  u16* wkvb_t=(u16*)A(2048ull*768*2);
  u16* whs_t =(u16*)A(1024ull*64*2);
  u16* whb_t =(u16*)A(1024ull*64*2);
  u16* wos_t =(u16*)A(1024ull*1024*2);
  u16* wob_t =(u16*)A(1024ull*1024*2);
  u16* w1_t  =(u16*)A(4096ull*1024*2);
  u16* w2_t  =(u16*)A(1024ull*4096*2);
  float* bqkv =(float*)A(3072*4);
  float* bkvb =(float*)A(2048*4);
  float* maskb=(float*)A(4096*4);
  float* xf32 =(float*)A(4194304ull*4);
  u16* xb16  =(u16*)A(4194304ull*2);
  u16* bertb =(u16*)A(3145728ull*2);
  u16* qkv_s =(u16*)A(4096ull*3072*2);   // must be immediately followed by qb (ff1 alias)
  u16* qb    =(u16*)A(4096ull*1024*2);
  u16* kvb   =(u16*)A(4096ull*2048*2);
  u16* vts   =(u16*)A(8388608);          // vtb must follow (yf32 alias)
  u16* vtb   =(u16*)A(8388608);
  u16* cats  =(u16*)A(8388608);
  u16* catb  =(u16*)A(8388608);
  // lifetime-checked aliases:
  u16*   ff1  = qkv_s;          // 32MB: dead (qkv_s,qb) after flash; written at ffn1
  float* zf   = (float*)kvb;    // 16MB: kvb dead after flash_b; zf written at wo_s
  float* yf32 = (float*)vts;    // 16MB: vts/vtb dead after flash; written at LN1
  u16*   yb16 = cats;           // 8MB: cats dead after wo_s; written at LN1
  (void)ws_size; (void)in_sizes; (void)n_in; (void)out_size;

  const dim3 t328(32,8);
  const size_t HWQ = 16ull*1024*64, HWK = 16ull*768*64, HWH = 16ull*64*64;

  k_cvt_bf16<<<4096,256,0,stream>>>(x_in, xb16, 1048576);
  k_cvt_bf16<<<3072,256,0,stream>>>(bert, bertb, 786432);
  k_maskbias<<<16,256,0,stream>>>(maskc, maskb, 4096);

  for(int i=0;i<6;i++){
    // ---- per-layer weight prep (fp32 -> bf16, [N][K] layouts) ----
    k_concat3<<<12,256,0,stream>>>(bqkv, s_bq+i*1024,1024, s_bk+i*1024,1024, s_bv+i*1024,1024);
    k_concat3<<<8,256,0,stream>>>(bkvb, b_bk+i*1024,1024, b_bv+i*1024,1024, nullptr,0);
    k_transpose_cvt_head<<<dim3(32,2,16),t328,0,stream>>>(s_wq+i*HWQ, wqkv_t,            1024);
    k_transpose_cvt_head<<<dim3(32,2,16),t328,0,stream>>>(s_wk+i*HWQ, wqkv_t+1024*1024,  1024);
    k_transpose_cvt_head<<<dim3(32,2,16),t328,0,stream>>>(s_wv+i*HWQ, wqkv_t+2048*1024,  1024);
    k_transpose_cvt_head<<<dim3(32,2,16),t328,0,stream>>>(b_wq+i*HWQ, wqb_t,             1024);
    k_transpose_cvt_head<<<dim3(24,2,16),t328,0,stream>>>(b_wk+i*HWK, wkvb_t,            768);
    k_transpose_cvt_head<<<dim3(24,2,16),t328,0,stream>>>(b_wv+i*HWK, wkvb_t+1024*768,   768);
    k_transpose_cvt_head<<<dim3(2,2,16), t328,0,stream>>>(s_wh+i*HWH, whs_t,             64);
    k_transpose_cvt_head<<<dim3(2,2,16), t328,0,stream>>>(b_wh+i*HWH, whb_t,             64);
    k_transpose_cvt<<<dim3(32,32), t328,0,stream>>>(s_wo+(size_t)i*1048576, wos_t, 1024,1024);
    k_transpose_cvt<<<dim3(32,32), t328,0,stream>>>(b_wo+(size_t)i*1048576, wob_t, 1024,1024);
    k_transpose_cvt<<<dim3(128,32),t328,0,stream>>>(w1 +(size_t)i*4194304, w1_t, 1024,4096);
    k_transpose_cvt<<<dim3(32,128),t328,0,stream>>>(w2 +(size_t)i*4194304, w2_t, 4096,1024);

    // ---- projections ----
    k_gemm_bt<true,false,false><<<dim3(24,32),256,0,stream>>>(xb16,  wqkv_t, bqkv,        nullptr, qkv_s, 3072,1024, 1.0f);
    k_gemm_bt<true,false,false><<<dim3(8,32), 256,0,stream>>>(xb16,  wqb_t,  b_bq+i*1024, nullptr, qb,    1024,1024, 1.0f);
    k_gemm_bt<true,false,false><<<dim3(16,32),256,0,stream>>>(bertb, wkvb_t, bkvb,        nullptr, kvb,   2048, 768, 1.0f);
    k_transpose_v<<<dim3(32,2,64),t328,0,stream>>>(qkv_s, 3072, 2048, vts);
    k_transpose_v<<<dim3(32,2,64),t328,0,stream>>>(kvb,   2048, 1024, vtb);

    // ---- attention (flash + fused wh) ----
    k_flash<<<dim3(16,64),256,0,stream>>>(qkv_s, 3072, qkv_s+1024, 3072, vts, whs_t, s_bh+i*1024, maskb, cats);
    k_flash<<<dim3(16,64),256,0,stream>>>(qb,    1024, kvb,        2048, vtb, whb_t, b_bh+i*1024, maskb, catb);

    // ---- output projections + residual, LN1 ----
    const float* xf = (i==0)? x_in : xf32;
    k_gemm_bt<false,false,true><<<dim3(8,32),256,0,stream>>>(cats, wos_t, s_bo+i*1024, xf, zf, 1024,1024, 0.5f);
    k_gemm_bt<false,false,true><<<dim3(8,32),256,0,stream>>>(catb, wob_t, b_bo+i*1024, zf, zf, 1024,1024, 0.5f);
    k_layernorm<<<4096,256,0,stream>>>(zf, ln1g+i*1024, ln1b+i*1024, yf32, yb16);

    // ---- FFN + residual, LN2 ----
    k_gemm_bt<true,true,false><<<dim3(32,32),256,0,stream>>>(yb16, w1_t, b1+i*4096, nullptr, ff1, 4096,1024, 1.0f);
    k_gemm_bt<false,false,true><<<dim3(8,32),256,0,stream>>>(ff1, w2_t, b2+i*1024, yf32, zf, 1024,4096, 1.0f);
    float* xo = (i==5)? (float*)d_out : xf32;
    k_layernorm<<<4096,256,0,stream>>>(zf, ln2g+i*1024, ln2b+i*1024, xo, xb16);
  }
}

// Round 2
// 3211.095 us; speedup vs baseline: 1.1103x; 1.1103x over previous
//
#include <hip/hip_runtime.h>
#include <hip/hip_bf16.h>
#include <cstdint>
#include <cstddef>

typedef unsigned short u16;
typedef __attribute__((ext_vector_type(8))) short s8v;     // 8 bf16 (A/B frag)
typedef __attribute__((ext_vector_type(4))) float f4v;     // C/D frag
typedef __attribute__((ext_vector_type(4))) unsigned short u16x4;

#define MFMA(A,B,C) __builtin_amdgcn_mfma_f32_16x16x32_bf16((A),(B),(C),0,0,0)

__device__ __forceinline__ u16 f2b(float f){
  union{float f; uint32_t u;} v; v.f=f;
  return (u16)((v.u + 0x7FFFu + ((v.u>>16)&1u))>>16);   // RNE
}

__device__ __forceinline__ void glds16(const u16* g, u16* l){
  __builtin_amdgcn_global_load_lds((const __attribute__((address_space(1))) uint32_t*)g,
                                   (__attribute__((address_space(3))) uint32_t*)l, 16, 0, 0);
}

// ---------------- elementwise f32 -> bf16 ----------------
__global__ void k_cvt_bf16(const float* __restrict__ src, u16* __restrict__ dst, int n4){
  int i = blockIdx.x*256 + threadIdx.x;
  if(i < n4){
    float4 v = ((const float4*)src)[i];
    u16x4 o; o.x=f2b(v.x); o.y=f2b(v.y); o.z=f2b(v.z); o.w=f2b(v.w);
    ((u16x4*)dst)[i] = o;
  }
}

// ---------------- mask -> additive bias ----------------
__global__ void k_maskbias(const unsigned char* __restrict__ m, float* __restrict__ dst, int n){
  int i = blockIdx.x*256 + threadIdx.x;
  if(i<n) dst[i] = m[i] ? -1e30f : 0.0f;
}

// ---------------- concat 1024-blocks of biases ----------------
__global__ void k_cat1024(float* __restrict__ dst, const float* a, const float* b,
                          const float* c, const float* d){
  int i = blockIdx.x*256 + threadIdx.x;
  const float* ps[4] = {a,b,c,d};
  dst[i] = ps[i>>10][i&1023];
}

__global__ void k_addbias(float* __restrict__ dst, const float* a, const float* b){
  int i = blockIdx.x*256 + threadIdx.x;
  dst[i] = a[i] + b[i];
}

// ---------------- transpose+cvt: src[K][N] f32 -> dst[N][ldd] bf16 (dst[n*ldd+k]) ----------------
__global__ void k_transpose_cvt(const float* __restrict__ src, u16* __restrict__ dst,
                                int K, int N, int ldd){
  __shared__ float t[32][33];
  int nb = blockIdx.x*32, kb = blockIdx.y*32;
  int tx = threadIdx.x, ty = threadIdx.y;          // (32,8)
#pragma unroll
  for(int i=0;i<32;i+=8) t[ty+i][tx] = src[(size_t)(kb+ty+i)*N + nb+tx];
  __syncthreads();
#pragma unroll
  for(int i=0;i<32;i+=8) dst[(size_t)(nb+ty+i)*ldd + kb+tx] = f2b(t[tx][ty+i]);
}

// ---------------- per-head transpose+cvt: src[H][K][64] f32 -> dst[H][64][K] bf16 ----------------
__global__ void k_transpose_cvt_head(const float* __restrict__ src, u16* __restrict__ dst, int K){
  __shared__ float t[32][33];
  const float* s = src + (size_t)blockIdx.z*K*64;
  u16* d = dst + (size_t)blockIdx.z*64*K;
  int kb = blockIdx.x*32, db = blockIdx.y*32;
  int tx=threadIdx.x, ty=threadIdx.y;
#pragma unroll
  for(int i=0;i<32;i+=8) t[ty+i][tx] = s[(size_t)(kb+ty+i)*64 + db+tx];
  __syncthreads();
#pragma unroll
  for(int i=0;i<32;i+=8) d[(size_t)(db+ty+i)*K + kb+tx] = f2b(t[tx][ty+i]);
}

// ---------------- V transpose: src[b*1024+s][lds_] cols col0+h*64+d -> dst[(b*16+h)*64+d][1024] ----------------
__global__ void k_transpose_v(const u16* __restrict__ src, int lds_, int col0, u16* __restrict__ dst){
  __shared__ u16 t[32][33];
  int bh = blockIdx.z; int b = bh>>4, h = bh&15;
  int s0 = blockIdx.x*32, d0 = blockIdx.y*32;
  int tx=threadIdx.x, ty=threadIdx.y;
#pragma unroll
  for(int i=0;i<32;i+=8)
    t[ty+i][tx] = src[(size_t)(b*1024 + s0+ty+i)*lds_ + col0 + h*64 + d0+tx];
  __syncthreads();
#pragma unroll
  for(int i=0;i<32;i+=8)
    dst[((size_t)bh*64 + d0+ty+i)*1024 + s0+tx] = t[tx][ty+i];
}

// ---------------- double-buffered GEMM: C[4096][N] = A[4096][K] @ Bt[N][K]^T ----------------
// out = alpha*(A@B + bias[col]) (+ resid[row*N+col]) ; optional relu; out bf16 or f32
// Requires gridDim.y == 32 (M=4096). XCD-swizzled block mapping.
template<bool OUTBF, bool RELU, bool RESID>
__global__ __launch_bounds__(256,4)
void k_gemm_bt(const u16* __restrict__ Ag_, const u16* __restrict__ Bg_,
               const float* __restrict__ bias, const float* __restrict__ resid,
               void* __restrict__ Cout, int N, int K, float alpha)
{
  __shared__ __align__(16) u16 lA[2][128*32];
  __shared__ __align__(16) u16 lB[2][128*32];
  const int tid = threadIdx.x;
  const int wave = tid>>6, lane = tid&63;
  const int m_ = lane&15, qd = lane>>4;
  const int wm = wave&1, wn = wave>>1;

  // XCD-aware swizzle: lin%8 = XCD (heuristic); each XCD gets a 4-block M band
  const int lin = blockIdx.y*gridDim.x + blockIdx.x;
  const int r8 = lin&7, q = lin>>3;
  const int m0 = ((r8<<2) | (q&3))<<7;
  const int n0 = (q>>2)<<7;

  f4v acc[4][4];
#pragma unroll
  for(int i2=0;i2<4;i2++)
#pragma unroll
    for(int j=0;j<4;j++){ f4v z={0.f,0.f,0.f,0.f}; acc[i2][j]=z; }

  const u16* Ag = Ag_ + (size_t)(m0 + (lane>>2))*K + (lane&3)*8;
  const u16* Bg = Bg_ + (size_t)(n0 + (lane>>2))*K + (lane&3)*8;
  const size_t rsk0 = (size_t)wave*16*K, rsk1 = (size_t)(wave+4)*16*K;
  const int w512a = wave*512, w512b = (wave+4)*512;

  // prologue: stage tile 0 into buffer 0
  glds16(Ag + rsk0, lA[0] + w512a);
  glds16(Ag + rsk1, lA[0] + w512b);
  glds16(Bg + rsk0, lB[0] + w512a);
  glds16(Bg + rsk1, lB[0] + w512b);

  int cur = 0;
  for(int k0=0; k0<K; k0+=32){
    __syncthreads();                      // drains glds for buf[cur]
    if(k0+32 < K){                        // prefetch next tile into buf[cur^1]
      const int kn = k0+32;
      glds16(Ag + rsk0 + kn, lA[cur^1] + w512a);
      glds16(Ag + rsk1 + kn, lA[cur^1] + w512b);
      glds16(Bg + rsk0 + kn, lB[cur^1] + w512a);
      glds16(Bg + rsk1 + kn, lB[cur^1] + w512b);
    }
    const u16* la = lA[cur];
    const u16* lb = lB[cur];
    s8v af[4], bf[4];
#pragma unroll
    for(int t=0;t<4;t++) af[t] = *(const s8v*)&la[((wm<<6) + (t<<4) + m_)*32 + (qd<<3)];
#pragma unroll
    for(int t=0;t<4;t++) bf[t] = *(const s8v*)&lb[((wn<<6) + (t<<4) + m_)*32 + (qd<<3)];
#pragma unroll
    for(int i2=0;i2<4;i2++)
#pragma unroll
      for(int j=0;j<4;j++) acc[i2][j] = MFMA(af[i2], bf[j], acc[i2][j]);
    cur ^= 1;
  }

#pragma unroll
  for(int i2=0;i2<4;i2++){
    const int row_b = m0 + (wm<<6) + (i2<<4) + (qd<<2);
#pragma unroll
    for(int j=0;j<4;j++){
      const int col = n0 + (wn<<6) + (j<<4) + m_;
      const float bv = bias[col];
#pragma unroll
      for(int r=0;r<4;r++){
        const int row = row_b + r;
        float v = (acc[i2][j][r] + bv)*alpha;
        if(RESID) v += resid[(size_t)row*N + col];
        if(RELU)  v = fmaxf(v, 0.0f);
        if(OUTBF) ((u16*)Cout)[(size_t)row*N + col] = f2b(v);
        else      ((float*)Cout)[(size_t)row*N + col] = v;
      }
    }
  }
}

// ---------------- flash attention + fused per-head wh linear ----------------
// grid (S/64, B*H); Q rows 64 per block (16/wave); K,V tiled by 32.
// Out[b*1024+q][ldo] cols h*64+j = ( softmax(Q K^T /8 + maskbias) V ) @ wh[h] + bh[h]
__global__ __launch_bounds__(256)
void k_flash(const u16* __restrict__ Q, int ldq,
             const u16* __restrict__ Kc, int ldk,
             const u16* __restrict__ Vt,
             const u16* __restrict__ wh_t, const float* __restrict__ bh,
             const float* __restrict__ maskb,
             u16* __restrict__ Out, int ldo)
{
  __shared__ __align__(16) u16 lK[32*72];
  __shared__ __align__(16) u16 lV[64*40];
  __shared__ __align__(16) u16 lP[4*16*40];
  __shared__ __align__(16) u16 lO[4*16*72];
  __shared__ __align__(16) float lMB[1024];

  const int tid = threadIdx.x;
  const int wave = tid>>6, lane = tid&63;
  const int m_ = lane&15, qd = lane>>4;
  const int bh_ = blockIdx.y; const int b = bh_>>4, h = bh_&15;
  const int q0 = blockIdx.x<<6;

  ((float4*)lMB)[tid] = ((const float4*)(maskb + (size_t)b*1024))[tid];

  const u16* qp = Q + (size_t)(b*1024 + q0 + wave*16 + m_)*ldq + h*64 + (qd<<3);
  s8v qa0 = *(const s8v*)qp;
  s8v qa1 = *(const s8v*)(qp + 32);

  f4v o[4];
#pragma unroll
  for(int nt=0;nt<4;nt++){ f4v z={0.f,0.f,0.f,0.f}; o[nt]=z; }
  float mi[4], li[4];
#pragma unroll
  for(int r=0;r<4;r++){ mi[r]=-1e20f; li[r]=0.0f; }

  const u16* Kbase = Kc + (size_t)(b*1024)*ldk + h*64;
  const u16* Vbase = Vt + (size_t)bh_*64*1024;
  u16* lPw = lP + wave*640;

  for(int t0=0; t0<1024; t0+=32){
    { // stage K (32x64, stride 72) and V (64x32, stride 40)
      int r = tid>>3, j = tid&7;
      *(s8v*)&lK[r*72 + (j<<3)] = *(const s8v*)(Kbase + (size_t)(t0+r)*ldk + (j<<3));
      int d = tid>>2, jc = tid&3;
      *(s8v*)&lV[d*40 + (jc<<3)] = *(const s8v*)(Vbase + (size_t)d*1024 + t0 + (jc<<3));
    }
    __syncthreads();

    f4v s0={0.f,0.f,0.f,0.f}, s1={0.f,0.f,0.f,0.f};
    {
      s8v kb00 = *(const s8v*)&lK[(m_)*72      + (qd<<3)];
      s8v kb01 = *(const s8v*)&lK[(m_)*72      + ((4+qd)<<3)];
      s8v kb10 = *(const s8v*)&lK[(16+m_)*72   + (qd<<3)];
      s8v kb11 = *(const s8v*)&lK[(16+m_)*72   + ((4+qd)<<3)];
      s0 = MFMA(qa0, kb00, s0); s0 = MFMA(qa1, kb01, s0);
      s1 = MFMA(qa0, kb10, s1); s1 = MFMA(qa1, kb11, s1);
    }
    const float bv0 = lMB[t0 + m_], bv1 = lMB[t0 + 16 + m_];
#pragma unroll
    for(int r=0;r<4;r++){ s0[r] = s0[r]*0.125f + bv0; s1[r] = s1[r]*0.125f + bv1; }

#pragma unroll
    for(int r=0;r<4;r++){
      float rm = fmaxf(s0[r], s1[r]);
      rm = fmaxf(rm, __shfl_xor(rm, 1)); rm = fmaxf(rm, __shfl_xor(rm, 2));
      rm = fmaxf(rm, __shfl_xor(rm, 4)); rm = fmaxf(rm, __shfl_xor(rm, 8));
      const float mn = fmaxf(mi[r], rm);
      const float al = __expf(mi[r] - mn);
      mi[r] = mn;
      const float p0 = __expf(s0[r]-mn), p1 = __expf(s1[r]-mn);
      float rs = p0 + p1;
      rs += __shfl_xor(rs,1); rs += __shfl_xor(rs,2);
      rs += __shfl_xor(rs,4); rs += __shfl_xor(rs,8);
      li[r] = li[r]*al + rs;
      o[0][r]*=al; o[1][r]*=al; o[2][r]*=al; o[3][r]*=al;
      lPw[((qd<<2)+r)*40 + m_]      = f2b(p0);
      lPw[((qd<<2)+r)*40 + 16 + m_] = f2b(p1);
    }
    // wave-local LDS round-trip: C-layout -> A-layout
    s8v pa = *(const s8v*)&lPw[m_*40 + (qd<<3)];
#pragma unroll
    for(int nt=0; nt<4; nt++){
      s8v vb = *(const s8v*)&lV[((nt<<4)+m_)*40 + (qd<<3)];
      o[nt] = MFMA(pa, vb, o[nt]);
    }
    __syncthreads();
  }

#pragma unroll
  for(int nt=0;nt<4;nt++)
#pragma unroll
    for(int r=0;r<4;r++) o[nt][r] /= li[r];

  // fused wh: write O (16x64) to LDS as A-operand, MFMA with wh_t[h] ([j][dk])
  u16* lOw = lO + wave*1152;
#pragma unroll
  for(int nt=0;nt<4;nt++)
#pragma unroll
    for(int r=0;r<4;r++)
      lOw[((qd<<2)+r)*72 + (nt<<4) + m_] = f2b(o[nt][r]);

  s8v oa0 = *(const s8v*)&lOw[m_*72 + (qd<<3)];
  s8v oa1 = *(const s8v*)&lOw[m_*72 + 32 + (qd<<3)];
  const u16* whp = wh_t + (size_t)h*64*64;
  f4v c2[4];
#pragma unroll
  for(int nt=0;nt<4;nt++){
    s8v wb0 = *(const s8v*)(whp + (size_t)((nt<<4)+m_)*64 + (qd<<3));
    s8v wb1 = *(const s8v*)(whp + (size_t)((nt<<4)+m_)*64 + 32 + (qd<<3));
    f4v z={0.f,0.f,0.f,0.f};
    z = MFMA(oa0, wb0, z);
    z = MFMA(oa1, wb1, z);
    c2[nt]=z;
  }
#pragma unroll
  for(int nt=0;nt<4;nt++){
    const int col = h*64 + (nt<<4) + m_;
    const float bb = bh[col];
#pragma unroll
    for(int r=0;r<4;r++){
      const int row = b*1024 + q0 + wave*16 + (qd<<2) + r;
      Out[(size_t)row*ldo + col] = f2b(c2[nt][r] + bb);
    }
  }
}

// ---------------- layernorm over 1024, dual-output (f32 + bf16) ----------------
__global__ __launch_bounds__(256)
void k_layernorm(const float* __restrict__ z, const float* __restrict__ g, const float* __restrict__ be,
                 float* __restrict__ outf, u16* __restrict__ outb)
{
  const int row = blockIdx.x, tid = threadIdx.x;
  const float4 x4 = ((const float4*)(z + (size_t)row*1024))[tid];
  float s  = x4.x + x4.y + x4.z + x4.w;
  float ss = x4.x*x4.x + x4.y*x4.y + x4.z*x4.z + x4.w*x4.w;
#pragma unroll
  for(int off=32; off; off>>=1){ s += __shfl_down(s,off); ss += __shfl_down(ss,off); }
  __shared__ float red[8];
  const int wave = tid>>6, lane = tid&63;
  if(lane==0){ red[wave]=s; red[4+wave]=ss; }
  __syncthreads();
  if(tid==0){
    float S=red[0]+red[1]+red[2]+red[3], SS=red[4]+red[5]+red[6]+red[7];
    float mu = S*(1.0f/1024.0f);
    float var = SS*(1.0f/1024.0f) - mu*mu;
    red[0]=mu; red[1]=rsqrtf(var + 1e-5f);
  }
  __syncthreads();
  const float mu=red[0], rs=red[1];
  const float4 g4 = ((const float4*)g)[tid];
  const float4 b4 = ((const float4*)be)[tid];
  float4 ov;
  ov.x = (x4.x-mu)*rs*g4.x + b4.x;
  ov.y = (x4.y-mu)*rs*g4.y + b4.y;
  ov.z = (x4.z-mu)*rs*g4.z + b4.z;
  ov.w = (x4.w-mu)*rs*g4.w + b4.w;
  ((float4*)(outf + (size_t)row*1024))[tid] = ov;
  u16x4 ob; ob.x=f2b(ov.x); ob.y=f2b(ov.y); ob.z=f2b(ov.z); ob.w=f2b(ov.w);
  ((u16x4*)(outb + (size_t)row*1024))[tid] = ob;
}

// =======================================================================
extern "C" void kernel_launch(void* const* d_in, const int* in_sizes, int n_in,
                              void* d_out, int out_size, void* d_ws, size_t ws_size,
                              hipStream_t stream)
{
  const float* x_in = (const float*)d_in[0];
  const float* bert = (const float*)d_in[1];
  const unsigned char* maskc = (const unsigned char*)d_in[2];
  const float* s_wq=(const float*)d_in[3];  const float* s_bq=(const float*)d_in[4];
  const float* s_wk=(const float*)d_in[5];  const float* s_bk=(const float*)d_in[6];
  const float* s_wv=(const float*)d_in[7];  const float* s_bv=(const float*)d_in[8];
  const float* s_wh=(const float*)d_in[9];  const float* s_bh=(const float*)d_in[10];
  const float* s_wo=(const float*)d_in[11]; const float* s_bo=(const float*)d_in[12];
  const float* b_wq=(const float*)d_in[13]; const float* b_bq=(const float*)d_in[14];
  const float* b_wk=(const float*)d_in[15]; const float* b_bk=(const float*)d_in[16];
  const float* b_wv=(const float*)d_in[17]; const float* b_bv=(const float*)d_in[18];
  const float* b_wh=(const float*)d_in[19]; const float* b_bh=(const float*)d_in[20];
  const float* b_wo=(const float*)d_in[21]; const float* b_bo=(const float*)d_in[22];
  const float* w1 =(const float*)d_in[23];  const float* b1 =(const float*)d_in[24];
  const float* w2 =(const float*)d_in[25];  const float* b2 =(const float*)d_in[26];
  const float* ln1g=(const float*)d_in[27]; const float* ln1b=(const float*)d_in[28];
  const float* ln2g=(const float*)d_in[29]; const float* ln2b=(const float*)d_in[30];

  char* p = (char*)d_ws;
  size_t off = 0;
  auto A = [&](size_t nbytes)->void*{ void* q = p + off; off += nbytes; off = (off+255)&~(size_t)255; return q; };

  u16* wqkv_t=(u16*)A(4096ull*1024*2);   // [Qs|Ks|Vs|Qb] x 1024
  u16* wkvb_t=(u16*)A(2048ull*768*2);    // [Kb|Vb] x 768
  u16* whs_t =(u16*)A(1024ull*64*2);
  u16* whb_t =(u16*)A(1024ull*64*2);
  u16* woc_t =(u16*)A(1024ull*2048*2);   // [n][ks|kb]
  u16* w1_t  =(u16*)A(4096ull*1024*2);
  u16* w2_t  =(u16*)A(1024ull*4096*2);
  float* bqkv =(float*)A(4096*4);
  float* bkvb =(float*)A(2048*4);
  float* boc  =(float*)A(1024*4);
  float* maskb=(float*)A(4096*4);
  float* xf32 =(float*)A(4194304ull*4);
  u16* xb16  =(u16*)A(4194304ull*2);
  u16* bertb =(u16*)A(3145728ull*2);
  u16* qkv4  =(u16*)A(4096ull*4096*2);   // 32MB
  u16* kvb   =(u16*)A(4096ull*2048*2);   // 16MB
  u16* vts   =(u16*)A(8388608);
  u16* vtb   =(u16*)A(8388608);
  u16* cat   =(u16*)A(4096ull*2048*2);   // 16MB  [ctx_s|ctx_b]
  // lifetime-checked aliases:
  u16*   ff1  = qkv4;           // 32MB: qkv4 dead after both flashes; written at ffn1
  float* zf   = (float*)kvb;    // 16MB: kvb dead after flash_b; written at wo GEMM
  float* yf32 = (float*)vts;    // 16MB: vts+vtb (adjacent) dead after flash; written at LN1
  u16*   yb16 = cat;            // 8MB of cat: cat dead after wo GEMM; written at LN1
  (void)ws_size; (void)in_sizes; (void)n_in; (void)out_size;

  const dim3 t328(32,8);
  const size_t HWQ = 16ull*1024*64, HWK = 16ull*768*64, HWH = 16ull*64*64;

  k_cvt_bf16<<<4096,256,0,stream>>>(x_in, xb16, 1048576);
  k_cvt_bf16<<<3072,256,0,stream>>>(bert, bertb, 786432);
  k_maskbias<<<16,256,0,stream>>>(maskc, maskb, 4096);

  for(int i=0;i<6;i++){
    // ---- per-layer weight prep (fp32 -> bf16, [N][K] layouts) ----
    k_cat1024<<<16,256,0,stream>>>(bqkv, s_bq+i*1024, s_bk+i*1024, s_bv+i*1024, b_bq+i*1024);
    k_cat1024<<<8, 256,0,stream>>>(bkvb, b_bk+i*1024, b_bv+i*1024, nullptr, nullptr);
    k_addbias<<<4, 256,0,stream>>>(boc, s_bo+i*1024, b_bo+i*1024);
    k_transpose_cvt_head<<<dim3(32,2,16),t328,0,stream>>>(s_wq+i*HWQ, wqkv_t,            1024);
    k_transpose_cvt_head<<<dim3(32,2,16),t328,0,stream>>>(s_wk+i*HWQ, wqkv_t+1024*1024,  1024);
    k_transpose_cvt_head<<<dim3(32,2,16),t328,0,stream>>>(s_wv+i*HWQ, wqkv_t+2048*1024,  1024);
    k_transpose_cvt_head<<<dim3(32,2,16),t328,0,stream>>>(b_wq+i*HWQ, wqkv_t+3072*1024,  1024);
    k_transpose_cvt_head<<<dim3(24,2,16),t328,0,stream>>>(b_wk+i*HWK, wkvb_t,            768);
    k_transpose_cvt_head<<<dim3(24,2,16),t328,0,stream>>>(b_wv+i*HWK, wkvb_t+1024*768,   768);
    k_transpose_cvt_head<<<dim3(2,2,16), t328,0,stream>>>(s_wh+i*HWH, whs_t,             64);
    k_transpose_cvt_head<<<dim3(2,2,16), t328,0,stream>>>(b_wh+i*HWH, whb_t,             64);
    k_transpose_cvt<<<dim3(32,32), t328,0,stream>>>(s_wo+(size_t)i*1048576, woc_t,        1024,1024, 2048);
    k_transpose_cvt<<<dim3(32,32), t328,0,stream>>>(b_wo+(size_t)i*1048576, woc_t+1024,   1024,1024, 2048);
    k_transpose_cvt<<<dim3(128,32),t328,0,stream>>>(w1 +(size_t)i*4194304, w1_t, 1024,4096, 1024);
    k_transpose_cvt<<<dim3(32,128),t328,0,stream>>>(w2 +(size_t)i*4194304, w2_t, 4096,1024, 4096);

    // ---- projections ----
    k_gemm_bt<true,false,false><<<dim3(32,32),256,0,stream>>>(xb16,  wqkv_t, bqkv, nullptr, qkv4, 4096,1024, 1.0f);
    k_gemm_bt<true,false,false><<<dim3(16,32),256,0,stream>>>(bertb, wkvb_t, bkvb, nullptr, kvb,  2048, 768, 1.0f);
    k_transpose_v<<<dim3(32,2,64),t328,0,stream>>>(qkv4, 4096, 2048, vts);
    k_transpose_v<<<dim3(32,2,64),t328,0,stream>>>(kvb,  2048, 1024, vtb);

    // ---- attention (flash + fused wh) ----
    k_flash<<<dim3(16,64),256,0,stream>>>(qkv4,      4096, qkv4+1024, 4096, vts, whs_t, s_bh+i*1024, maskb, cat,      2048);
    k_flash<<<dim3(16,64),256,0,stream>>>(qkv4+3072, 4096, kvb,       2048, vtb, whb_t, b_bh+i*1024, maskb, cat+1024, 2048);

    // ---- fused output projection (self+bert) + residual, LN1 ----
    const float* xf = (i==0)? x_in : xf32;
    k_gemm_bt<false,false,true><<<dim3(8,32),256,0,stream>>>(cat, woc_t, boc, xf, zf, 1024,2048, 0.5f);
    k_layernorm<<<4096,256,0,stream>>>(zf, ln1g+i*1024, ln1b+i*1024, yf32, yb16);

    // ---- FFN + residual, LN2 ----
    k_gemm_bt<true,true,false><<<dim3(32,32),256,0,stream>>>(yb16, w1_t, b1+i*4096, nullptr, ff1, 4096,1024, 1.0f);
    k_gemm_bt<false,false,true><<<dim3(8,32),256,0,stream>>>(ff1, w2_t, b2+i*1024, yf32, zf, 1024,4096, 1.0f);
    float* xo = (i==5)? (float*)d_out : xf32;
    k_layernorm<<<4096,256,0,stream>>>(zf, ln2g+i*1024, ln2b+i*1024, xo, xb16);
  }
}

// Round 3
// 2431.236 us; speedup vs baseline: 1.4664x; 1.3208x over previous
//
#include <hip/hip_runtime.h>
#include <hip/hip_bf16.h>
#include <cstdint>
#include <cstddef>

typedef unsigned short u16;
typedef __attribute__((ext_vector_type(8))) short s8v;     // 8 bf16 (A/B frag)
typedef __attribute__((ext_vector_type(4))) float f4v;     // C/D frag
typedef __attribute__((ext_vector_type(4))) unsigned short u16x4;

#define MFMA(A,B,C) __builtin_amdgcn_mfma_f32_16x16x32_bf16((A),(B),(C),0,0,0)

__device__ __forceinline__ u16 f2b(float f){
  union{float f; uint32_t u;} v; v.f=f;
  return (u16)((v.u + 0x7FFFu + ((v.u>>16)&1u))>>16);   // RNE
}
__device__ __forceinline__ u16 f2b_t(float f){           // truncate (P matrix only)
  union{float f; uint32_t u;} v; v.f=f;
  return (u16)(v.u>>16);
}

__device__ __forceinline__ void glds16(const u16* g, u16* l){
  __builtin_amdgcn_global_load_lds((const __attribute__((address_space(1))) uint32_t*)g,
                                   (__attribute__((address_space(3))) uint32_t*)l, 16, 0, 0);
}

// ---------------- elementwise f32 -> bf16 ----------------
__global__ void k_cvt_bf16(const float* __restrict__ src, u16* __restrict__ dst, int n4){
  int i = blockIdx.x*256 + threadIdx.x;
  if(i < n4){
    float4 v = ((const float4*)src)[i];
    u16x4 o; o.x=f2b(v.x); o.y=f2b(v.y); o.z=f2b(v.z); o.w=f2b(v.w);
    ((u16x4*)dst)[i] = o;
  }
}

// ---------------- mask -> additive bias (includes fixed softmax max M0=8) ----------------
__global__ void k_maskbias(const unsigned char* __restrict__ m, float* __restrict__ dst, int n){
  int i = blockIdx.x*256 + threadIdx.x;
  if(i<n) dst[i] = m[i] ? -1e30f : -8.0f;
}

// ---------------- per-layer bias prep (one launch) ----------------
__global__ void k_bias_prep(float* __restrict__ bqkv, float* __restrict__ bkvb, float* __restrict__ boc,
                            const float* a0, const float* a1, const float* a2, const float* a3,
                            const float* k0, const float* k1, const float* o0, const float* o1){
  int i = blockIdx.x*256 + threadIdx.x;          // 0..7167
  if(i < 4096){
    const float* ps[4] = {a0,a1,a2,a3};
    bqkv[i] = ps[i>>10][i&1023];
  } else if(i < 6144){
    int j = i - 4096;
    bkvb[j] = (j<1024) ? k0[j] : k1[j-1024];
  } else if(i < 7168){
    int j = i - 6144;
    boc[j] = o0[j] + o1[j];
  }
}

// ---------------- transpose+cvt: src[K][N] f32 -> dst[N][ldd] bf16 ----------------
__global__ void k_transpose_cvt(const float* __restrict__ src, u16* __restrict__ dst,
                                int K, int N, int ldd){
  __shared__ float t[32][33];
  int nb = blockIdx.x*32, kb = blockIdx.y*32;
  int tx = threadIdx.x, ty = threadIdx.y;          // (32,8)
#pragma unroll
  for(int i=0;i<32;i+=8) t[ty+i][tx] = src[(size_t)(kb+ty+i)*N + nb+tx];
  __syncthreads();
#pragma unroll
  for(int i=0;i<32;i+=8) dst[(size_t)(nb+ty+i)*ldd + kb+tx] = f2b(t[tx][ty+i]);
}

// ---------------- wo pair: two [1024][1024] -> woc_t[n][2048] (col halves) ----------------
__global__ void k_wo2(const float* __restrict__ s0, const float* __restrict__ s1, u16* __restrict__ dst){
  __shared__ float t[32][33];
  const float* src = blockIdx.z ? s1 : s0;
  int nb = blockIdx.x*32, kb = blockIdx.y*32;
  int tx=threadIdx.x, ty=threadIdx.y;
#pragma unroll
  for(int i=0;i<32;i+=8) t[ty+i][tx] = src[(size_t)(kb+ty+i)*1024 + nb+tx];
  __syncthreads();
#pragma unroll
  for(int i=0;i<32;i+=8) dst[(size_t)(nb+ty+i)*2048 + blockIdx.z*1024 + kb+tx] = f2b(t[tx][ty+i]);
}

// ---------------- per-head transpose+cvt, up to 4 sources ----------------
struct TCH { const float* s0; const float* s1; const float* s2; const float* s3;
             u16* d0; u16* d1; u16* d2; u16* d3; };
__global__ void k_tch(TCH t, int K){
  __shared__ float sm[32][33];
  int si = blockIdx.z>>4, h = blockIdx.z&15;
  const float* sp = (si==0? t.s0 : si==1? t.s1 : si==2? t.s2 : t.s3) + (size_t)h*K*64;
  u16* dp        = (si==0? t.d0 : si==1? t.d1 : si==2? t.d2 : t.d3) + (size_t)h*64*K;
  int kb = blockIdx.x*32, db = blockIdx.y*32;
  int tx=threadIdx.x, ty=threadIdx.y;
#pragma unroll
  for(int i=0;i<32;i+=8) sm[ty+i][tx] = sp[(size_t)(kb+ty+i)*64 + db+tx];
  __syncthreads();
#pragma unroll
  for(int i=0;i<32;i+=8) dp[(size_t)(db+ty+i)*K + kb+tx] = f2b(sm[tx][ty+i]);
}

// ---------------- V transposes (self+bert fused) ----------------
__global__ void k_tv2(const u16* __restrict__ s0, const u16* __restrict__ s1, u16* __restrict__ dst){
  __shared__ u16 t[32][33];
  int zz = blockIdx.z>>6; int bh = blockIdx.z&63;
  const u16* src = zz ? s1 : s0;
  int lds_ = zz ? 2048 : 4096;
  int col0 = zz ? 1024 : 2048;
  u16* d = dst + (size_t)zz*4194304 + (size_t)bh*64*1024;
  int b = bh>>4, h = bh&15;
  int s0_ = blockIdx.x*32, d0 = blockIdx.y*32;
  int tx=threadIdx.x, ty=threadIdx.y;
#pragma unroll
  for(int i=0;i<32;i+=8)
    t[ty+i][tx] = src[(size_t)(b*1024 + s0_+ty+i)*lds_ + col0 + h*64 + d0+tx];
  __syncthreads();
#pragma unroll
  for(int i=0;i<32;i+=8)
    d[(size_t)(d0+ty+i)*1024 + s0_+tx] = t[tx][ty+i];
}

// ---------------- double-buffered GEMM: C[4096][N] = A[4096][K] @ Bt[N][K]^T ----------------
// XOR-swizzled LDS chunks (conflict-free fragment reads).
template<bool OUTBF, bool RELU, bool RESID>
__global__ __launch_bounds__(256,4)
void k_gemm_bt(const u16* __restrict__ Ag_, const u16* __restrict__ Bg_,
               const float* __restrict__ bias, const float* __restrict__ resid,
               void* __restrict__ Cout, int N, int K, float alpha)
{
  __shared__ __align__(16) u16 lA[2][128*32];
  __shared__ __align__(16) u16 lB[2][128*32];
  const int tid = threadIdx.x;
  const int wave = tid>>6, lane = tid&63;
  const int m_ = lane&15, qd = lane>>4;
  const int wm = wave&1, wn = wave>>1;

  const int lin = blockIdx.y*gridDim.x + blockIdx.x;
  const int r8 = lin&7, q = lin>>3;
  const int m0 = ((r8<<2) | (q&3))<<7;
  const int n0 = (q>>2)<<7;

  f4v acc[4][4];
#pragma unroll
  for(int i2=0;i2<4;i2++)
#pragma unroll
    for(int j=0;j<4;j++){ f4v z={0.f,0.f,0.f,0.f}; acc[i2][j]=z; }

  // staging: lane L -> row L>>2, slot L&3; fetch global chunk (L&3)^((L>>3)&3)
  const int gch = ((lane&3) ^ ((lane>>3)&3))<<3;
  const u16* Ag = Ag_ + (size_t)(m0 + (lane>>2))*K + gch;
  const u16* Bg = Bg_ + (size_t)(n0 + (lane>>2))*K + gch;
  const size_t rsk0 = (size_t)wave*16*K, rsk1 = (size_t)(wave+4)*16*K;
  const int w512a = wave*512, w512b = (wave+4)*512;
  // fragment read slot: qd ^ ((m_>>1)&3)
  const int swz = (qd ^ ((m_>>1)&3))<<3;

  glds16(Ag + rsk0, lA[0] + w512a);
  glds16(Ag + rsk1, lA[0] + w512b);
  glds16(Bg + rsk0, lB[0] + w512a);
  glds16(Bg + rsk1, lB[0] + w512b);

  int cur = 0;
  for(int k0=0; k0<K; k0+=32){
    __syncthreads();
    if(k0+32 < K){
      const int kn = k0+32;
      glds16(Ag + rsk0 + kn, lA[cur^1] + w512a);
      glds16(Ag + rsk1 + kn, lA[cur^1] + w512b);
      glds16(Bg + rsk0 + kn, lB[cur^1] + w512a);
      glds16(Bg + rsk1 + kn, lB[cur^1] + w512b);
    }
    const u16* la = lA[cur];
    const u16* lb = lB[cur];
    s8v af[4], bf[4];
#pragma unroll
    for(int t=0;t<4;t++) af[t] = *(const s8v*)&la[((wm<<6) + (t<<4) + m_)*32 + swz];
#pragma unroll
    for(int t=0;t<4;t++) bf[t] = *(const s8v*)&lb[((wn<<6) + (t<<4) + m_)*32 + swz];
#pragma unroll
    for(int i2=0;i2<4;i2++)
#pragma unroll
      for(int j=0;j<4;j++) acc[i2][j] = MFMA(af[i2], bf[j], acc[i2][j]);
    cur ^= 1;
  }

#pragma unroll
  for(int i2=0;i2<4;i2++){
    const int row_b = m0 + (wm<<6) + (i2<<4) + (qd<<2);
#pragma unroll
    for(int j=0;j<4;j++){
      const int col = n0 + (wn<<6) + (j<<4) + m_;
      const float bv = bias[col];
#pragma unroll
      for(int r=0;r<4;r++){
        const int row = row_b + r;
        float v = (acc[i2][j][r] + bv)*alpha;
        if(RESID) v += resid[(size_t)row*N + col];
        if(RELU)  v = fmaxf(v, 0.0f);
        if(OUTBF) ((u16*)Cout)[(size_t)row*N + col] = f2b(v);
        else      ((float*)Cout)[(size_t)row*N + col] = v;
      }
    }
  }
}

// ---------------- fused flash attention (self+bert via z) + per-head wh linear ----------------
// Fixed-max softmax: p = exp(s/8 + maskbias - 8); row-sum deferred to epilogue.
// grid (16, 64, 2); 64 Q rows/block, K-tile 64, glds16-staged XOR-swizzled K and V^T.
__global__ __launch_bounds__(256,4)
void k_flash2(const u16* __restrict__ qkv4, const u16* __restrict__ kvb,
              const u16* __restrict__ vts,
              const u16* __restrict__ whs, const u16* __restrict__ whb,
              const float* __restrict__ bh0, const float* __restrict__ bh1,
              const float* __restrict__ maskb, u16* __restrict__ Out)
{
  __shared__ __align__(16) u16 lK[64*64];
  __shared__ __align__(16) u16 lV[64*64];
  __shared__ __align__(16) u16 lP[4*16*72];
  __shared__ __align__(16) float lMB[1024];

  const int tid = threadIdx.x;
  const int wave = tid>>6, lane = tid&63;
  const int m_ = lane&15, qd = lane>>4;
  const int z = blockIdx.z;
  const int bh_ = blockIdx.y; const int b = bh_>>4, h = bh_&15;
  const int q0 = blockIdx.x<<6;

  const u16* Q; const u16* K; const u16* V; const u16* wh; const float* bhp;
  int ldq, ldk;
  if(z==0){ Q=qkv4;      ldq=4096; K=qkv4+1024; ldk=4096; V=vts;          wh=whs; bhp=bh0; }
  else    { Q=qkv4+3072; ldq=4096; K=kvb;       ldk=2048; V=vts+4194304;  wh=whb; bhp=bh1; }

  ((float4*)lMB)[tid] = ((const float4*)(maskb + (size_t)b*1024))[tid];

  // Q fragments (A layout): rows wave*16+m_, k-chunks qd and qd+4
  const u16* qp = Q + (size_t)(b*1024 + q0 + wave*16 + m_)*ldq + h*64 + (qd<<3);
  s8v qa0 = *(const s8v*)qp;
  s8v qa1 = *(const s8v*)(qp + 32);

  // staging lane geometry: row L>>3, slot L&7; fetch global chunk (L&7)^(L>>3)
  const int rl = lane>>3;
  const int gc8 = ((lane&7) ^ rl)<<3;
  const u16* kgl = K + (size_t)(b*1024 + wave*16 + rl)*ldk + h*64 + gc8;
  const u16* vgl = V + ((size_t)bh_*64 + wave*16 + rl)*1024 + gc8;
  u16* lKw = lK + wave*1024;
  u16* lVw = lV + wave*1024;

  // fragment read swizzle: slot c0 = qd ^ (m_&7); second k-half = c0 ^ 4
  const int c0 = ((qd ^ (m_&7)))<<3;
  const int c1 = c0 ^ 32;

  f4v o[4];
#pragma unroll
  for(int nt=0;nt<4;nt++){ f4v zr={0.f,0.f,0.f,0.f}; o[nt]=zr; }
  float li[4] = {0.f,0.f,0.f,0.f};
  u16* lPw = lP + wave*1152;

  for(int t0=0; t0<1024; t0+=64){
    __syncthreads();                              // protect lK/lV from overwrite
    glds16(kgl + (size_t)t0*ldk,          lKw);
    glds16(kgl + (size_t)(t0+8)*ldk,      lKw + 512);
    glds16(vgl + t0,                      lVw);
    glds16(vgl + t0 + 8192,               lVw + 512);
    __syncthreads();                              // staging complete

    // QK^T: s[jt] covers t-cols t0 + jt*16 + m_
    f4v s[4];
#pragma unroll
    for(int jt=0;jt<4;jt++){
      const int rowb = (jt<<4) + m_;
      s8v kb0 = *(const s8v*)&lK[rowb*64 + c0];
      s8v kb1 = *(const s8v*)&lK[rowb*64 + c1];
      f4v zr={0.f,0.f,0.f,0.f};
      zr = MFMA(qa0, kb0, zr);
      zr = MFMA(qa1, kb1, zr);
      s[jt] = zr;
    }

    // softmax (fixed max) + P write
#pragma unroll
    for(int jt=0;jt<4;jt++){
      const float mb = lMB[t0 + (jt<<4) + m_];
#pragma unroll
      for(int r=0;r<4;r++){
        const float pf = __expf(fmaf(s[jt][r], 0.125f, mb));
        li[r] += pf;
        lPw[((qd<<2)+r)*72 + (jt<<4) + m_] = f2b_t(pf);
      }
    }

    // P (A layout) x V^T (B layout)
    s8v pa0 = *(const s8v*)&lPw[m_*72 + (qd<<3)];
    s8v pa1 = *(const s8v*)&lPw[m_*72 + 32 + (qd<<3)];
#pragma unroll
    for(int nt=0;nt<4;nt++){
      const int rowb = (nt<<4) + m_;
      s8v vb0 = *(const s8v*)&lV[rowb*64 + c0];
      s8v vb1 = *(const s8v*)&lV[rowb*64 + c1];
      o[nt] = MFMA(pa0, vb0, o[nt]);
      o[nt] = MFMA(pa1, vb1, o[nt]);
    }
  }

  // row-sum reduction (cols live across the 16 lanes sharing qd)
#pragma unroll
  for(int r=0;r<4;r++){
    float s_ = li[r];
    s_ += __shfl_xor(s_,1); s_ += __shfl_xor(s_,2);
    s_ += __shfl_xor(s_,4); s_ += __shfl_xor(s_,8);
    const float inv = 1.0f/s_;
#pragma unroll
    for(int nt=0;nt<4;nt++) o[nt][r] *= inv;
  }

  // fused wh: O (16x64) -> LDS (A layout), MFMA with wh[h]
#pragma unroll
  for(int nt=0;nt<4;nt++)
#pragma unroll
    for(int r=0;r<4;r++)
      lPw[((qd<<2)+r)*72 + (nt<<4) + m_] = f2b(o[nt][r]);

  s8v oa0 = *(const s8v*)&lPw[m_*72 + (qd<<3)];
  s8v oa1 = *(const s8v*)&lPw[m_*72 + 32 + (qd<<3)];
  const u16* whp = wh + (size_t)h*64*64;
#pragma unroll
  for(int nt=0;nt<4;nt++){
    s8v wb0 = *(const s8v*)(whp + (size_t)((nt<<4)+m_)*64 + (qd<<3));
    s8v wb1 = *(const s8v*)(whp + (size_t)((nt<<4)+m_)*64 + 32 + (qd<<3));
    f4v c2={0.f,0.f,0.f,0.f};
    c2 = MFMA(oa0, wb0, c2);
    c2 = MFMA(oa1, wb1, c2);
    const int col = (z<<10) + (h<<6) + (nt<<4) + m_;
    const float bb = bhp[(h<<6) + (nt<<4) + m_];
#pragma unroll
    for(int r=0;r<4;r++){
      const int row = b*1024 + q0 + wave*16 + (qd<<2) + r;
      Out[(size_t)row*2048 + col] = f2b(c2[r] + bb);
    }
  }
}

// ---------------- layernorm over 1024, dual-output (f32 + bf16) ----------------
__global__ __launch_bounds__(256)
void k_layernorm(const float* __restrict__ z, const float* __restrict__ g, const float* __restrict__ be,
                 float* __restrict__ outf, u16* __restrict__ outb)
{
  const int row = blockIdx.x, tid = threadIdx.x;
  const float4 x4 = ((const float4*)(z + (size_t)row*1024))[tid];
  float s  = x4.x + x4.y + x4.z + x4.w;
  float ss = x4.x*x4.x + x4.y*x4.y + x4.z*x4.z + x4.w*x4.w;
#pragma unroll
  for(int off=32; off; off>>=1){ s += __shfl_down(s,off); ss += __shfl_down(ss,off); }
  __shared__ float red[8];
  const int wave = tid>>6, lane = tid&63;
  if(lane==0){ red[wave]=s; red[4+wave]=ss; }
  __syncthreads();
  if(tid==0){
    float S=red[0]+red[1]+red[2]+red[3], SS=red[4]+red[5]+red[6]+red[7];
    float mu = S*(1.0f/1024.0f);
    float var = SS*(1.0f/1024.0f) - mu*mu;
    red[0]=mu; red[1]=rsqrtf(var + 1e-5f);
  }
  __syncthreads();
  const float mu=red[0], rs=red[1];
  const float4 g4 = ((const float4*)g)[tid];
  const float4 b4 = ((const float4*)be)[tid];
  float4 ov;
  ov.x = (x4.x-mu)*rs*g4.x + b4.x;
  ov.y = (x4.y-mu)*rs*g4.y + b4.y;
  ov.z = (x4.z-mu)*rs*g4.z + b4.z;
  ov.w = (x4.w-mu)*rs*g4.w + b4.w;
  ((float4*)(outf + (size_t)row*1024))[tid] = ov;
  u16x4 ob; ob.x=f2b(ov.x); ob.y=f2b(ov.y); ob.z=f2b(ov.z); ob.w=f2b(ov.w);
  ((u16x4*)(outb + (size_t)row*1024))[tid] = ob;
}

// =======================================================================
extern "C" void kernel_launch(void* const* d_in, const int* in_sizes, int n_in,
                              void* d_out, int out_size, void* d_ws, size_t ws_size,
                              hipStream_t stream)
{
  const float* x_in = (const float*)d_in[0];
  const float* bert = (const float*)d_in[1];
  const unsigned char* maskc = (const unsigned char*)d_in[2];
  const float* s_wq=(const float*)d_in[3];  const float* s_bq=(const float*)d_in[4];
  const float* s_wk=(const float*)d_in[5];  const float* s_bk=(const float*)d_in[6];
  const float* s_wv=(const float*)d_in[7];  const float* s_bv=(const float*)d_in[8];
  const float* s_wh=(const float*)d_in[9];  const float* s_bh=(const float*)d_in[10];
  const float* s_wo=(const float*)d_in[11]; const float* s_bo=(const float*)d_in[12];
  const float* b_wq=(const float*)d_in[13]; const float* b_bq=(const float*)d_in[14];
  const float* b_wk=(const float*)d_in[15]; const float* b_bk=(const float*)d_in[16];
  const float* b_wv=(const float*)d_in[17]; const float* b_bv=(const float*)d_in[18];
  const float* b_wh=(const float*)d_in[19]; const float* b_bh=(const float*)d_in[20];
  const float* b_wo=(const float*)d_in[21]; const float* b_bo=(const float*)d_in[22];
  const float* w1 =(const float*)d_in[23];  const float* b1 =(const float*)d_in[24];
  const float* w2 =(const float*)d_in[25];  const float* b2 =(const float*)d_in[26];
  const float* ln1g=(const float*)d_in[27]; const float* ln1b=(const float*)d_in[28];
  const float* ln2g=(const float*)d_in[29]; const float* ln2b=(const float*)d_in[30];

  char* p = (char*)d_ws;
  size_t off = 0;
  auto A = [&](size_t nbytes)->void*{ void* q = p + off; off += nbytes; off = (off+255)&~(size_t)255; return q; };

  u16* wqkv_t=(u16*)A(4096ull*1024*2);   // [Qs|Ks|Vs|Qb] x 1024
  u16* wkvb_t=(u16*)A(2048ull*768*2);    // [Kb|Vb] x 768
  u16* whs_t =(u16*)A(1024ull*64*2);
  u16* whb_t =(u16*)A(1024ull*64*2);
  u16* woc_t =(u16*)A(1024ull*2048*2);   // [n][ks|kb]
  u16* w1_t  =(u16*)A(4096ull*1024*2);
  u16* w2_t  =(u16*)A(1024ull*4096*2);
  float* bqkv =(float*)A(4096*4);
  float* bkvb =(float*)A(2048*4);
  float* boc  =(float*)A(1024*4);
  float* maskb=(float*)A(4096*4);
  float* xf32 =(float*)A(4194304ull*4);
  u16* xb16  =(u16*)A(4194304ull*2);
  u16* bertb =(u16*)A(3145728ull*2);
  u16* qkv4  =(u16*)A(4096ull*4096*2);   // 32MB
  u16* kvb   =(u16*)A(4096ull*2048*2);   // 16MB
  u16* vts   =(u16*)A(8388608);          // self V^T ; bert V^T at vts+4194304 elems
  u16* vtb   =(u16*)A(8388608);
  u16* cat   =(u16*)A(4096ull*2048*2);   // 16MB  [ctx_s|ctx_b]
  (void)vtb;
  // lifetime-checked aliases:
  u16*   ff1  = qkv4;           // 32MB: qkv4 dead after flash; written at ffn1
  float* zf   = (float*)kvb;    // 16MB: kvb dead after flash; written at wo GEMM
  float* yf32 = (float*)vts;    // 16MB: vts(+vtb) dead after flash; written at LN1
  u16*   yb16 = cat;            // 8MB of cat: cat dead after wo GEMM; written at LN1
  (void)ws_size; (void)in_sizes; (void)n_in; (void)out_size;

  const dim3 t328(32,8);
  const size_t HWQ = 16ull*1024*64, HWK = 16ull*768*64, HWH = 16ull*64*64;

  k_cvt_bf16<<<4096,256,0,stream>>>(x_in, xb16, 1048576);
  k_cvt_bf16<<<3072,256,0,stream>>>(bert, bertb, 786432);
  k_maskbias<<<16,256,0,stream>>>(maskc, maskb, 4096);

  for(int i=0;i<6;i++){
    // ---- per-layer weight prep ----
    k_bias_prep<<<28,256,0,stream>>>(bqkv, bkvb, boc,
        s_bq+i*1024, s_bk+i*1024, s_bv+i*1024, b_bq+i*1024,
        b_bk+i*1024, b_bv+i*1024, s_bo+i*1024, b_bo+i*1024);
    TCH t1 = { s_wq+i*HWQ, s_wk+i*HWQ, s_wv+i*HWQ, b_wq+i*HWQ,
               wqkv_t, wqkv_t+1024*1024, wqkv_t+2048*1024, wqkv_t+3072*1024 };
    k_tch<<<dim3(32,2,64),t328,0,stream>>>(t1, 1024);
    TCH t2 = { b_wk+i*HWK, b_wv+i*HWK, nullptr, nullptr,
               wkvb_t, wkvb_t+1024*768, nullptr, nullptr };
    k_tch<<<dim3(24,2,32),t328,0,stream>>>(t2, 768);
    TCH t3 = { s_wh+i*HWH, b_wh+i*HWH, nullptr, nullptr,
               whs_t, whb_t, nullptr, nullptr };
    k_tch<<<dim3(2,2,32),t328,0,stream>>>(t3, 64);
    k_wo2<<<dim3(32,32,2),t328,0,stream>>>(s_wo+(size_t)i*1048576, b_wo+(size_t)i*1048576, woc_t);
    k_transpose_cvt<<<dim3(128,32),t328,0,stream>>>(w1 +(size_t)i*4194304, w1_t, 1024,4096, 1024);
    k_transpose_cvt<<<dim3(32,128),t328,0,stream>>>(w2 +(size_t)i*4194304, w2_t, 4096,1024, 4096);

    // ---- projections ----
    k_gemm_bt<true,false,false><<<dim3(32,32),256,0,stream>>>(xb16,  wqkv_t, bqkv, nullptr, qkv4, 4096,1024, 1.0f);
    k_gemm_bt<true,false,false><<<dim3(16,32),256,0,stream>>>(bertb, wkvb_t, bkvb, nullptr, kvb,  2048, 768, 1.0f);
    k_tv2<<<dim3(32,2,128),t328,0,stream>>>(qkv4, kvb, vts);

    // ---- attention (fused self+bert flash + wh) ----
    k_flash2<<<dim3(16,64,2),256,0,stream>>>(qkv4, kvb, vts, whs_t, whb_t,
                                             s_bh+i*1024, b_bh+i*1024, maskb, cat);

    // ---- fused output projection (self+bert) + residual, LN1 ----
    const float* xf = (i==0)? x_in : xf32;
    k_gemm_bt<false,false,true><<<dim3(8,32),256,0,stream>>>(cat, woc_t, boc, xf, zf, 1024,2048, 0.5f);
    k_layernorm<<<4096,256,0,stream>>>(zf, ln1g+i*1024, ln1b+i*1024, yf32, yb16);

    // ---- FFN + residual, LN2 ----
    k_gemm_bt<true,true,false><<<dim3(32,32),256,0,stream>>>(yb16, w1_t, b1+i*4096, nullptr, ff1, 4096,1024, 1.0f);
    k_gemm_bt<false,false,true><<<dim3(8,32),256,0,stream>>>(ff1, w2_t, b2+i*1024, yf32, zf, 1024,4096, 1.0f);
    float* xo = (i==5)? (float*)d_out : xf32;
    k_layernorm<<<4096,256,0,stream>>>(zf, ln2g+i*1024, ln2b+i*1024, xo, xb16);
  }
}